// Round 23
// baseline (544.919 us; speedup 1.0000x reference)
//
#include <hip/hip_runtime.h>

// ---------------------------------------------------------------------------
// Fused MHA: qkv = x@Wqkv+b ; causal attention ; out = attn@Wproj+b
// B=4, T=2048, C=2048, H=16, D=128. fp32 in/out, bf16 MFMA internally.
// GEMM = m201 8-PHASE schedule (R20). attn = R21 XCD-affine + T15 overlap:
// per tile, QK(g0);QK(g1);SM0;PV0;SM1;PV1 in one scheduling region so the
// compiler interleaves softmax VALU with the other group's MFMA bursts.
// ---------------------------------------------------------------------------

typedef __bf16 bf16;
typedef __bf16 bf16x8 __attribute__((ext_vector_type(8)));
typedef __bf16 bf16x4 __attribute__((ext_vector_type(4)));
typedef float f32x4 __attribute__((ext_vector_type(4)));

__device__ __forceinline__ void gload_lds16(const void* g, void* l) {
  __builtin_amdgcn_global_load_lds(
      (const __attribute__((address_space(1))) void*)g,
      (__attribute__((address_space(3))) void*)l, 16, 0, 0);
}

// ---------------------------------------------------------------------------
// transpose body: W [R][C] fp32 -> WT [C][R] bf16, 64x64 tile (G13).
__device__ __forceinline__ void transpose_body(
    const float* __restrict__ in, bf16* __restrict__ out, int R, int C,
    int bx, int by, int t, bf16* tile /*[64*64] swizzled*/) {
  const int r0 = by * 64, c0 = bx * 64;
  const int ri = t >> 2, cseg = (t & 3) * 16;
  const float4* src = (const float4*)&in[(size_t)(r0 + ri) * C + c0 + cseg];
  float4 f0 = src[0], f1 = src[1], f2 = src[2], f3 = src[3];
  bf16x8 h0 = {(bf16)f0.x, (bf16)f0.y, (bf16)f0.z, (bf16)f0.w,
               (bf16)f1.x, (bf16)f1.y, (bf16)f1.z, (bf16)f1.w};
  bf16x8 h1 = {(bf16)f2.x, (bf16)f2.y, (bf16)f2.z, (bf16)f2.w,
               (bf16)f3.x, (bf16)f3.y, (bf16)f3.z, (bf16)f3.w};
  const int kx = (ri & 7) << 3;
  *(bf16x8*)&tile[ri * 64 + (cseg ^ kx)] = h0;
  *(bf16x8*)&tile[ri * 64 + ((cseg + 8) ^ kx)] = h1;
  __syncthreads();
  const int oj = t >> 2, rseg = (t & 3) * 16;
  bf16 v[16];
#pragma unroll
  for (int i = 0; i < 16; ++i) {
    const int rr = rseg + i;
    v[i] = tile[rr * 64 + (oj ^ ((rr & 7) << 3))];
  }
  bf16* dst = &out[(size_t)(c0 + oj) * R + r0 + rseg];
  *(bf16x8*)dst = *(bf16x8*)&v[0];
  *(bf16x8*)(dst + 8) = *(bf16x8*)&v[8];
}

// ---------------------------------------------------------------------------
// merged prep: blocks 0..2047 cast x; 2048..5119 transpose Wqkv (96x32);
// 5120..6143 transpose Wproj (32x32). One launch -> streams overlap.
__global__ __launch_bounds__(256) void prep_kernel(
    const float* __restrict__ x, bf16* __restrict__ xb,
    const float* __restrict__ Wqkv, bf16* __restrict__ wqkvT,
    const float* __restrict__ Wproj, bf16* __restrict__ wprojT) {
  __shared__ bf16 tile[64 * 64];  // used by transpose roles only
  const int b = blockIdx.x, t = threadIdx.x;
  if (b < 2048) {  // cast fp32 -> bf16, 8 elems/thread, grid-stride
    for (int i = b * 256 + t; i < 2097152; i += 2048 * 256) {
      const float4* p = (const float4*)x + (size_t)i * 2;
      float4 a = p[0], c = p[1];
      bf16x8 o8 = {(bf16)a.x, (bf16)a.y, (bf16)a.z, (bf16)a.w,
                   (bf16)c.x, (bf16)c.y, (bf16)c.z, (bf16)c.w};
      *(bf16x8*)(xb + (size_t)i * 8) = o8;
    }
  } else if (b < 5120) {  // Wqkv [2048][6144] -> wqkvT [6144][2048]
    const int tb = b - 2048;
    transpose_body(Wqkv, wqkvT, 2048, 6144, tb % 96, tb / 96, t, tile);
  } else {  // Wproj [2048][2048] -> wprojT [2048][2048]
    const int tb = b - 5120;
    transpose_body(Wproj, wprojT, 2048, 2048, tb % 32, tb / 32, t, tile);
  }
}

// ---------------------------------------------------------------------------
// 256x256 GEMM, m201 8-PHASE schedule (R20, unchanged).
template <int EPI>
__global__ __launch_bounds__(512, 2) void gemm256(
    const bf16* __restrict__ A, const bf16* __restrict__ BT,
    const float* __restrict__ bias, int M, int N, int K,
    float* __restrict__ outf, bf16* __restrict__ qb, bf16* __restrict__ kb,
    bf16* __restrict__ vtb) {
  __shared__ bf16 As[2][2][256 * 32];  // 64 KB
  __shared__ bf16 Bs[2][2][256 * 32];  // 64 KB
  const int tid = threadIdx.x;
  const int lane = tid & 63, w = tid >> 6;
  const int wm = w >> 2, wn = w & 3;
  const int lr = lane & 15, lg = lane >> 4;

  // XCD column-major walk (M/256 == 32 == 8 XCDs x 4 m-tiles, both grids)
  const int xcd = blockIdx.x & 7, local = blockIdx.x >> 3;
  const int mt = xcd * 4 + (local & 3), nt = local >> 2;
  const int m0 = mt * 256, n0 = nt * 256;

  // stage one 16KB half-tile (kh, operand) of K-tile kt into dbuf kt&1.
  auto STAGE_H = [&](int skh, int sisB, int kt) {
    const bf16* src = sisB ? BT : A;
    const int r0 = sisB ? n0 : m0;
    bf16* lb = sisB ? &Bs[kt & 1][skh][0] : &As[kt & 1][skh][0];
#pragma unroll
    for (int c = 0; c < 2; ++c) {
      const int chunk = w * 2 + c;                    // 0..15 (1KB chunks)
      const int row = chunk * 16 + (lane >> 2);       // 0..255
      const int col = ((lane & 3) * 8) ^ (((row >> 3) & 1) << 4);
      gload_lds16(src + (size_t)(r0 + row) * K + kt * 64 + skh * 32 + col,
                  (char*)lb + chunk * 1024);
    }
  };
  // fragment reads (swizzled): logical (row, lg*8..+7) of K-half kh
  auto LDA = [&](int d, int kh, int mi) -> bf16x8 {
    const int row = wm * 128 + mi * 16 + lr;
    return *(const bf16x8*)((const char*)&As[d][kh][0] +
                            ((row * 64 + lg * 16) ^ ((lr >> 3) << 5)));
  };
  auto LDB = [&](int d, int kh, int ni) -> bf16x8 {
    const int row = wn * 64 + ni * 16 + lr;
    return *(const bf16x8*)((const char*)&Bs[d][kh][0] +
                            ((row * 64 + lg * 16) ^ ((lr >> 3) << 5)));
  };

  f32x4 acc[8][4] = {};
  bf16x8 bfr[4];
  const int NT = K >> 6;

  // one phase: quadrant (d, kh, mh); stage half-tile (skh,sB) of tile st;
  // vm: -1 none, 4 counted, 0 drain.
  auto PHASE = [&](int d, int kh, int mh, int st, int skh, int sB, int vm) {
    if (mh == 0) {
#pragma unroll
      for (int ni = 0; ni < 4; ++ni) bfr[ni] = LDB(d, kh, ni);
    }
    bf16x8 af4[4];
#pragma unroll
    for (int j = 0; j < 4; ++j) af4[j] = LDA(d, kh, mh * 4 + j);
    if (st < NT) STAGE_H(skh, sB, st);
    __builtin_amdgcn_s_barrier();
    asm volatile("s_waitcnt lgkmcnt(0)" ::: "memory");
    __builtin_amdgcn_sched_barrier(0);
    __builtin_amdgcn_s_setprio(1);
#pragma unroll
    for (int j = 0; j < 4; ++j)
#pragma unroll
      for (int ni = 0; ni < 4; ++ni)
        acc[mh * 4 + j][ni] = __builtin_amdgcn_mfma_f32_16x16x32_bf16(
            af4[j], bfr[ni], acc[mh * 4 + j][ni], 0, 0, 0);
    __builtin_amdgcn_s_setprio(0);
    if (vm == 4) asm volatile("s_waitcnt vmcnt(4)" ::: "memory");
    else if (vm == 0) asm volatile("s_waitcnt vmcnt(0)" ::: "memory");
    __builtin_amdgcn_s_barrier();
  };

  // prologue: tile0 fully + tile1 kh0 (12 loads); first 8 (tile0) landed
  STAGE_H(0, 0, 0);
  STAGE_H(0, 1, 0);
  STAGE_H(1, 0, 0);
  STAGE_H(1, 1, 0);
  STAGE_H(0, 0, 1);
  STAGE_H(0, 1, 1);
  asm volatile("s_waitcnt vmcnt(4)" ::: "memory");
  __builtin_amdgcn_s_barrier();

  for (int a = 0; a < NT; a += 2) {
    const int b = a + 1;
    const bool p34 = (a + 2 < NT);
    PHASE(0, 0, 0, b, 1, 0, -1);              // ph1: stage A(b)kh1
    PHASE(0, 0, 1, b, 1, 1, -1);              // ph2: stage B(b)kh1
    PHASE(0, 1, 0, a + 2, 0, 0, -1);          // ph3: stage A(a+2)kh0
    PHASE(0, 1, 1, a + 2, 0, 1, p34 ? 4 : 0); // ph4 (+vmcnt)
    PHASE(1, 0, 0, a + 2, 1, 0, -1);          // ph5: stage A(a+2)kh1
    PHASE(1, 0, 1, a + 2, 1, 1, -1);          // ph6: stage B(a+2)kh1
    PHASE(1, 1, 0, b + 2, 0, 0, -1);          // ph7: stage A(b+2)kh0
    PHASE(1, 1, 1, b + 2, 0, 1, p34 ? 4 : 0); // ph8 (+vmcnt)
  }

  // epilogue: C/D layout col=lane&15, row=(lane>>4)*4+r  [m89/m91]
#pragma unroll
  for (int mi = 0; mi < 8; ++mi) {
    const int mbase = m0 + wm * 128 + mi * 16 + lg * 4;
#pragma unroll
    for (int ni = 0; ni < 4; ++ni) {
      const int n = n0 + wn * 64 + ni * 16 + lr;
      const float bv = bias[n];
      if (EPI == 1) {
#pragma unroll
        for (int r = 0; r < 4; ++r)
          outf[(size_t)(mbase + r) * N + n] = acc[mi][ni][r] + bv;
      } else {
        const int which = n >> 11;           // 0=q 1=k 2=v
        const int cc = n & 2047, h = cc >> 7, dd = cc & 127;
        const int b = mbase >> 11, t0 = mbase & 2047;  // 4-row group never
        const int bh = b * 16 + h;                     // crosses b boundary
        if (which == 2) {
          bf16x4 pk;
#pragma unroll
          for (int r = 0; r < 4; ++r) pk[r] = (bf16)(acc[mi][ni][r] + bv);
          *(bf16x4*)&vtb[((size_t)bh * 128 + dd) * 2048 + t0] = pk;
        } else {
          bf16* dst = (which == 0) ? qb : kb;
#pragma unroll
          for (int r = 0; r < 4; ++r)
            dst[((size_t)bh * 2048 + t0 + r) * 128 + dd] =
                (bf16)(acc[mi][ni][r] + bv);
        }
      }
    }
  }
}

// ---------------------------------------------------------------------------
// Flash attention, causal, WORK-BALANCED pairing, SWAPPED QK^T, KVBLK=128,
// XCD-AFFINE GRID (64,8). T15 overlap (this round): per tile, both groups'
// QK^T MFMAs issue first, then SM0/PV0/SM1/PV1 follow in ONE scheduling
// region (single setprio bracket, masks unconditional: qq>=128 => no-op),
// so the compiler hides softmax VALU under the other group's MFMA bursts.
__global__ __launch_bounds__(512) void attn_kernel(
    const bf16* __restrict__ qb, const bf16* __restrict__ kb,
    const bf16* __restrict__ vtb, bf16* __restrict__ ob) {
  __shared__ bf16 Ks[2][128 * 128];  // 64 KB, swizzled
  __shared__ bf16 Vs[2][128 * 128];  // 64 KB, swizzled ([d][t])
  __shared__ bf16 Ps[8][16 * 64];    // 16 KB, swizzled
  const int tid = threadIdx.x, lane = tid & 63, w = tid >> 6;
  const int bh = blockIdx.x;             // XCD affinity: xcd = bh % 8
  const int qtA = blockIdx.y;            // 0..7
  const int qtB = 15 - qtA;              // 8..15
  const int qt_w = (w < 4) ? qtA : qtB;  // this wave's q-tile
  const int wq = w & 3;                  // wave slot within its q-tile
  const int lr = lane & 15, lg = lane >> 4;
  const int q0 = qt_w * 128;
  const size_t base = (size_t)bh * (2048 * 128);
  const int rswz = (lr & 7) << 3;  // row-XOR (element domain)

  // hoist Q frags; fold (1/sqrt(D))*log2(e) so softmax runs in exp2 domain
  const float qscale = 0.08838834764831845f * 1.4426950408889634f;
  bf16x8 qf[2][4];
#pragma unroll
  for (int g = 0; g < 2; ++g) {
    const bf16* qp =
        qb + base + (size_t)(q0 + g * 64 + wq * 16 + lr) * 128 + lg * 8;
#pragma unroll
    for (int kk = 0; kk < 4; ++kk) {
      bf16x8 t = *(const bf16x8*)(qp + kk * 32);
#pragma unroll
      for (int e = 0; e < 8; ++e) t[e] = (bf16)((float)t[e] * qscale);
      qf[g][kk] = t;
    }
  }

  f32x4 o[2][8] = {};
  float mst[2] = {-1e30f, -1e30f};  // running max for q = lr (exp2 domain)
  float lst[2] = {0.f, 0.f};        // running sum for q = lr

  // stage 128-wide tile kt: K 32KB + V 32KB; 8 gload_lds/thread.
  auto STAGE = [&](int bsel, int kt) {
#pragma unroll
    for (int c = 0; c < 4; ++c) {
      const int off = w * 1024 + c * 8192 + lane * 16;  // byte off in 32KB
      const int row = off >> 8, ce = (off & 255) >> 1;  // 256B rows
      gload_lds16(kb + base + (size_t)(kt * 128 + row) * 128 +
                      (ce ^ ((row & 7) << 3)),
                  (char*)Ks[bsel] + w * 1024 + c * 8192);
      gload_lds16(vtb + base + (size_t)row * 2048 + kt * 128 +
                      (ce ^ ((row & 7) << 3)),
                  (char*)Vs[bsel] + w * 1024 + c * 8192);
    }
  };

  const int nst = qtB + 1;  // 128-wide tiles (covers A's range too)
  STAGE(0, 0);              // 8 outstanding
  for (int kt = 0; kt < nst; ++kt) {
    const int cur = kt & 1;
    if (kt + 1 < nst) {
      STAGE(cur ^ 1, kt + 1);  // 8 more in flight
      asm volatile("s_waitcnt vmcnt(8)" ::: "memory");  // tile kt landed
    } else {
      asm volatile("s_waitcnt vmcnt(0)" ::: "memory");
    }
    __builtin_amdgcn_s_barrier();  // all waves' staging of kt visible
    __builtin_amdgcn_sched_barrier(0);

    const bf16* Kc = Ks[cur];
    const bf16* Vc = Vs[cur];

    // S' = K Q^T (swapped): s[j], k_rel = j*16+lg*4+r (0..127), q = lr
    auto QK = [&](const bf16x8 (&qfg)[4], f32x4 (&s)[8]) {
#pragma unroll
      for (int kk = 0; kk < 4; ++kk)
#pragma unroll
        for (int j = 0; j < 8; ++j) {
          const bf16x8 kf = *(const bf16x8*)&Kc[(j * 16 + lr) * 128 +
                                               ((kk * 32 + lg * 8) ^ rswz)];
          s[j] = __builtin_amdgcn_mfma_f32_16x16x32_bf16(kf, qfg[kk], s[j],
                                                         0, 0, 0);
        }
    };
    // causal mask; when gbrel >= 2, qq >= 128 > k_rel(max 127) -> no-op
    auto MASK = [&](f32x4 (&s)[8], int gbrel) {
      const int qq = gbrel * 64 + wq * 16 + lr;
#pragma unroll
      for (int j = 0; j < 8; ++j)
#pragma unroll
        for (int r = 0; r < 4; ++r)
          if (j * 16 + lg * 4 + r > qq) s[j][r] = -1e30f;
    };
    // online softmax (in-lane, exp2 domain) + P store + PV for group g
    auto SMPV = [&](int g, f32x4 (&s)[8]) {
      float pm;
      {
        float a0 = -1e30f, a1 = -1e30f;
#pragma unroll
        for (int j = 0; j < 8; j += 2) {
          a0 = fmaxf(a0, fmaxf(fmaxf(s[j][0], s[j][1]),
                               fmaxf(s[j][2], s[j][3])));
          a1 = fmaxf(a1, fmaxf(fmaxf(s[j + 1][0], s[j + 1][1]),
                               fmaxf(s[j + 1][2], s[j + 1][3])));
        }
        pm = fmaxf(a0, a1);
      }
      pm = fmaxf(pm, __shfl_xor(pm, 16));
      pm = fmaxf(pm, __shfl_xor(pm, 32));
      // T13 defer-max: rescale only when some row's max grew by >8
      if (__any(pm > mst[g] + 8.0f)) {
        const float mnew = fmaxf(mst[g], pm);
        const float alpha = __builtin_amdgcn_exp2f(mst[g] - mnew);
        mst[g] = mnew;
        lst[g] *= alpha;
#pragma unroll
        for (int r = 0; r < 4; ++r) {  // o rows: q = lg*4+r
          const float av = __shfl(alpha, (lane & 48) | (lg * 4 + r));
#pragma unroll
          for (int n = 0; n < 8; ++n) o[g][n][r] *= av;
        }
      }
      float rs = 0.f;
#pragma unroll
      for (int j = 0; j < 8; ++j)
#pragma unroll
        for (int r = 0; r < 4; ++r) {
          const float p = __builtin_amdgcn_exp2f(s[j][r] - mst[g]);
          s[j][r] = p;
          rs += p;
        }
      rs += __shfl_xor(rs, 16);
      rs += __shfl_xor(rs, 32);
      lst[g] += rs;
      // P @ V in two K=64 halves through the per-wave Ps buffer
#pragma unroll
      for (int h = 0; h < 2; ++h) {
#pragma unroll
        for (int j2 = 0; j2 < 4; ++j2) {
          const int j = h * 4 + j2;
          bf16x4 pw;
#pragma unroll
          for (int r = 0; r < 4; ++r) pw[r] = (bf16)s[j][r];
          *(bf16x4*)&Ps[w][lr * 64 + ((j2 * 16 + lg * 4) ^ rswz)] = pw;
        }
        bf16x8 pf[2];
#pragma unroll
        for (int kk = 0; kk < 2; ++kk)
          pf[kk] = *(const bf16x8*)&Ps[w][lr * 64 +
                                         ((kk * 32 + lg * 8) ^ rswz)];
#pragma unroll
        for (int n = 0; n < 8; ++n)
#pragma unroll
          for (int kk = 0; kk < 2; ++kk) {
            const bf16x8 vf = *(const bf16x8*)&Vc[(n * 16 + lr) * 128 +
                                                 ((h * 64 + kk * 32 +
                                                   lg * 8) ^ rswz)];
            o[g][n] = __builtin_amdgcn_mfma_f32_16x16x32_bf16(
                pf[kk], vf, o[g][n], 0, 0, 0);
          }
      }
    };

    const int gbrel0 = 2 * qt_w - 2 * kt;  // g=0 rel position; g=1 is +1
    if (gbrel0 >= 0) {  // both groups active: fused single-region body
      __builtin_amdgcn_s_setprio(1);
      f32x4 s0[8] = {}, s1[8] = {};
      QK(qf[0], s0);
      QK(qf[1], s1);
      MASK(s0, gbrel0);
      MASK(s1, gbrel0 + 1);
      SMPV(0, s0);
      SMPV(1, s1);
      __builtin_amdgcn_s_setprio(0);
    } else if (gbrel0 == -1) {  // only g=1 active (diagonal boundary tile)
      __builtin_amdgcn_s_setprio(1);
      f32x4 s1[8] = {};
      QK(qf[1], s1);
      MASK(s1, 0);
      SMPV(1, s1);
      __builtin_amdgcn_s_setprio(0);
    }
    __builtin_amdgcn_sched_barrier(0);
    __builtin_amdgcn_s_barrier();  // all reads of buf cur done before next
    __builtin_amdgcn_sched_barrier(0);  // STAGE overwrites it
  }

  // write attn-out as bf16 [B*T][C]; lst holds q=lr, o rows are q=lg*4+r
  const int b = bh >> 4, h = bh & 15;
#pragma unroll
  for (int g = 0; g < 2; ++g)
#pragma unroll
    for (int r = 0; r < 4; ++r) {
      const float inv = 1.0f / __shfl(lst[g], (lane & 48) | (lg * 4 + r));
      const int t = q0 + g * 64 + wq * 16 + lg * 4 + r;
      bf16* dst = ob + ((size_t)(b * 2048 + t)) * 2048 + h * 128;
#pragma unroll
      for (int n = 0; n < 8; ++n) dst[n * 16 + lr] = (bf16)(o[g][n][r] * inv);
    }
}

// ---------------------------------------------------------------------------
extern "C" void kernel_launch(void* const* d_in, const int* in_sizes, int n_in,
                              void* d_out, int out_size, void* d_ws,
                              size_t ws_size, hipStream_t stream) {
  const float* x = (const float*)d_in[0];      // [4,2048,2048]
  const float* Wqkv = (const float*)d_in[1];   // [2048,6144]
  const float* bqkv = (const float*)d_in[2];   // [6144]
  const float* Wproj = (const float*)d_in[3];  // [2048,2048]
  const float* bproj = (const float*)d_in[4];  // [2048]
  float* out = (float*)d_out;                  // [8192,2048] fp32

  char* ws = (char*)d_ws;  // needs ~192 MiB
  bf16* xb     = (bf16*)(ws);                  // 33554432 B  x bf16
  bf16* wqkvT  = (bf16*)(ws + 33554432);       // 25165824 B  Wqkv^T
  bf16* wprojT = (bf16*)(ws + 58720256);       //  8388608 B  Wproj^T
  bf16* qb     = (bf16*)(ws + 67108864);       // 33554432 B  Q [BH][T][D]
  bf16* kb     = (bf16*)(ws + 100663296);      // 33554432 B  K [BH][T][D]
  bf16* vtb    = (bf16*)(ws + 134217728);      // 33554432 B  V^T [BH][D][T]
  bf16* ab     = (bf16*)(ws + 167772160);      // 33554432 B  attn out bf16

  prep_kernel<<<6144, 256, 0, stream>>>(x, xb, Wqkv, wqkvT, Wproj, wprojT);
  gemm256<0><<<768, 512, 0, stream>>>(xb, wqkvT, bqkv, 8192, 6144, 2048,
                                      nullptr, qb, kb, vtb);
  attn_kernel<<<dim3(64, 8), 512, 0, stream>>>(qb, kb, vtb, ab);
  gemm256<1><<<256, 512, 0, stream>>>(ab, wprojT, bproj, 8192, 2048, 2048,
                                      out, nullptr, nullptr, nullptr);
}

// Round 24
// 426.497 us; speedup vs baseline: 1.2777x; 1.2777x over previous
//
#include <hip/hip_runtime.h>

// ---------------------------------------------------------------------------
// Fused MHA: qkv = x@Wqkv+b ; causal attention ; out = attn@Wproj+b
// B=4, T=2048, C=2048, H=16, D=128. fp32 in/out, bf16 MFMA internally.
// GEMM = m201 8-PHASE schedule (R20, 982 TF). attn = R21/R22 XCD-affine
// version (R23's T15 fusion spilled S-tiles to scratch -> reverted).
// Prep merged into one launch (R22).
// ---------------------------------------------------------------------------

typedef __bf16 bf16;
typedef __bf16 bf16x8 __attribute__((ext_vector_type(8)));
typedef __bf16 bf16x4 __attribute__((ext_vector_type(4)));
typedef float f32x4 __attribute__((ext_vector_type(4)));

__device__ __forceinline__ void gload_lds16(const void* g, void* l) {
  __builtin_amdgcn_global_load_lds(
      (const __attribute__((address_space(1))) void*)g,
      (__attribute__((address_space(3))) void*)l, 16, 0, 0);
}

// ---------------------------------------------------------------------------
// transpose body: W [R][C] fp32 -> WT [C][R] bf16, 64x64 tile (G13).
__device__ __forceinline__ void transpose_body(
    const float* __restrict__ in, bf16* __restrict__ out, int R, int C,
    int bx, int by, int t, bf16* tile /*[64*64] swizzled*/) {
  const int r0 = by * 64, c0 = bx * 64;
  const int ri = t >> 2, cseg = (t & 3) * 16;
  const float4* src = (const float4*)&in[(size_t)(r0 + ri) * C + c0 + cseg];
  float4 f0 = src[0], f1 = src[1], f2 = src[2], f3 = src[3];
  bf16x8 h0 = {(bf16)f0.x, (bf16)f0.y, (bf16)f0.z, (bf16)f0.w,
               (bf16)f1.x, (bf16)f1.y, (bf16)f1.z, (bf16)f1.w};
  bf16x8 h1 = {(bf16)f2.x, (bf16)f2.y, (bf16)f2.z, (bf16)f2.w,
               (bf16)f3.x, (bf16)f3.y, (bf16)f3.z, (bf16)f3.w};
  const int kx = (ri & 7) << 3;
  *(bf16x8*)&tile[ri * 64 + (cseg ^ kx)] = h0;
  *(bf16x8*)&tile[ri * 64 + ((cseg + 8) ^ kx)] = h1;
  __syncthreads();
  const int oj = t >> 2, rseg = (t & 3) * 16;
  bf16 v[16];
#pragma unroll
  for (int i = 0; i < 16; ++i) {
    const int rr = rseg + i;
    v[i] = tile[rr * 64 + (oj ^ ((rr & 7) << 3))];
  }
  bf16* dst = &out[(size_t)(c0 + oj) * R + r0 + rseg];
  *(bf16x8*)dst = *(bf16x8*)&v[0];
  *(bf16x8*)(dst + 8) = *(bf16x8*)&v[8];
}

// ---------------------------------------------------------------------------
// merged prep: blocks 0..2047 cast x; 2048..5119 transpose Wqkv (96x32);
// 5120..6143 transpose Wproj (32x32). One launch -> streams overlap.
__global__ __launch_bounds__(256) void prep_kernel(
    const float* __restrict__ x, bf16* __restrict__ xb,
    const float* __restrict__ Wqkv, bf16* __restrict__ wqkvT,
    const float* __restrict__ Wproj, bf16* __restrict__ wprojT) {
  __shared__ bf16 tile[64 * 64];  // used by transpose roles only
  const int b = blockIdx.x, t = threadIdx.x;
  if (b < 2048) {  // cast fp32 -> bf16, 8 elems/thread, grid-stride
    for (int i = b * 256 + t; i < 2097152; i += 2048 * 256) {
      const float4* p = (const float4*)x + (size_t)i * 2;
      float4 a = p[0], c = p[1];
      bf16x8 o8 = {(bf16)a.x, (bf16)a.y, (bf16)a.z, (bf16)a.w,
                   (bf16)c.x, (bf16)c.y, (bf16)c.z, (bf16)c.w};
      *(bf16x8*)(xb + (size_t)i * 8) = o8;
    }
  } else if (b < 5120) {  // Wqkv [2048][6144] -> wqkvT [6144][2048]
    const int tb = b - 2048;
    transpose_body(Wqkv, wqkvT, 2048, 6144, tb % 96, tb / 96, t, tile);
  } else {  // Wproj [2048][2048] -> wprojT [2048][2048]
    const int tb = b - 5120;
    transpose_body(Wproj, wprojT, 2048, 2048, tb % 32, tb / 32, t, tile);
  }
}

// ---------------------------------------------------------------------------
// 256x256 GEMM, m201 8-PHASE schedule (R20, unchanged).
template <int EPI>
__global__ __launch_bounds__(512, 2) void gemm256(
    const bf16* __restrict__ A, const bf16* __restrict__ BT,
    const float* __restrict__ bias, int M, int N, int K,
    float* __restrict__ outf, bf16* __restrict__ qb, bf16* __restrict__ kb,
    bf16* __restrict__ vtb) {
  __shared__ bf16 As[2][2][256 * 32];  // 64 KB
  __shared__ bf16 Bs[2][2][256 * 32];  // 64 KB
  const int tid = threadIdx.x;
  const int lane = tid & 63, w = tid >> 6;
  const int wm = w >> 2, wn = w & 3;
  const int lr = lane & 15, lg = lane >> 4;

  // XCD column-major walk (M/256 == 32 == 8 XCDs x 4 m-tiles, both grids)
  const int xcd = blockIdx.x & 7, local = blockIdx.x >> 3;
  const int mt = xcd * 4 + (local & 3), nt = local >> 2;
  const int m0 = mt * 256, n0 = nt * 256;

  // stage one 16KB half-tile (kh, operand) of K-tile kt into dbuf kt&1.
  auto STAGE_H = [&](int skh, int sisB, int kt) {
    const bf16* src = sisB ? BT : A;
    const int r0 = sisB ? n0 : m0;
    bf16* lb = sisB ? &Bs[kt & 1][skh][0] : &As[kt & 1][skh][0];
#pragma unroll
    for (int c = 0; c < 2; ++c) {
      const int chunk = w * 2 + c;                    // 0..15 (1KB chunks)
      const int row = chunk * 16 + (lane >> 2);       // 0..255
      const int col = ((lane & 3) * 8) ^ (((row >> 3) & 1) << 4);
      gload_lds16(src + (size_t)(r0 + row) * K + kt * 64 + skh * 32 + col,
                  (char*)lb + chunk * 1024);
    }
  };
  // fragment reads (swizzled): logical (row, lg*8..+7) of K-half kh
  auto LDA = [&](int d, int kh, int mi) -> bf16x8 {
    const int row = wm * 128 + mi * 16 + lr;
    return *(const bf16x8*)((const char*)&As[d][kh][0] +
                            ((row * 64 + lg * 16) ^ ((lr >> 3) << 5)));
  };
  auto LDB = [&](int d, int kh, int ni) -> bf16x8 {
    const int row = wn * 64 + ni * 16 + lr;
    return *(const bf16x8*)((const char*)&Bs[d][kh][0] +
                            ((row * 64 + lg * 16) ^ ((lr >> 3) << 5)));
  };

  f32x4 acc[8][4] = {};
  bf16x8 bfr[4];
  const int NT = K >> 6;

  // one phase: quadrant (d, kh, mh); stage half-tile (skh,sB) of tile st;
  // vm: -1 none, 4 counted, 0 drain.
  auto PHASE = [&](int d, int kh, int mh, int st, int skh, int sB, int vm) {
    if (mh == 0) {
#pragma unroll
      for (int ni = 0; ni < 4; ++ni) bfr[ni] = LDB(d, kh, ni);
    }
    bf16x8 af4[4];
#pragma unroll
    for (int j = 0; j < 4; ++j) af4[j] = LDA(d, kh, mh * 4 + j);
    if (st < NT) STAGE_H(skh, sB, st);
    __builtin_amdgcn_s_barrier();
    asm volatile("s_waitcnt lgkmcnt(0)" ::: "memory");
    __builtin_amdgcn_sched_barrier(0);
    __builtin_amdgcn_s_setprio(1);
#pragma unroll
    for (int j = 0; j < 4; ++j)
#pragma unroll
      for (int ni = 0; ni < 4; ++ni)
        acc[mh * 4 + j][ni] = __builtin_amdgcn_mfma_f32_16x16x32_bf16(
            af4[j], bfr[ni], acc[mh * 4 + j][ni], 0, 0, 0);
    __builtin_amdgcn_s_setprio(0);
    if (vm == 4) asm volatile("s_waitcnt vmcnt(4)" ::: "memory");
    else if (vm == 0) asm volatile("s_waitcnt vmcnt(0)" ::: "memory");
    __builtin_amdgcn_s_barrier();
  };

  // prologue: tile0 fully + tile1 kh0 (12 loads); first 8 (tile0) landed
  STAGE_H(0, 0, 0);
  STAGE_H(0, 1, 0);
  STAGE_H(1, 0, 0);
  STAGE_H(1, 1, 0);
  STAGE_H(0, 0, 1);
  STAGE_H(0, 1, 1);
  asm volatile("s_waitcnt vmcnt(4)" ::: "memory");
  __builtin_amdgcn_s_barrier();

  for (int a = 0; a < NT; a += 2) {
    const int b = a + 1;
    const bool p34 = (a + 2 < NT);
    PHASE(0, 0, 0, b, 1, 0, -1);              // ph1: stage A(b)kh1
    PHASE(0, 0, 1, b, 1, 1, -1);              // ph2: stage B(b)kh1
    PHASE(0, 1, 0, a + 2, 0, 0, -1);          // ph3: stage A(a+2)kh0
    PHASE(0, 1, 1, a + 2, 0, 1, p34 ? 4 : 0); // ph4 (+vmcnt)
    PHASE(1, 0, 0, a + 2, 1, 0, -1);          // ph5: stage A(a+2)kh1
    PHASE(1, 0, 1, a + 2, 1, 1, -1);          // ph6: stage B(a+2)kh1
    PHASE(1, 1, 0, b + 2, 0, 0, -1);          // ph7: stage A(b+2)kh0
    PHASE(1, 1, 1, b + 2, 0, 1, p34 ? 4 : 0); // ph8 (+vmcnt)
  }

  // epilogue: C/D layout col=lane&15, row=(lane>>4)*4+r  [m89/m91]
#pragma unroll
  for (int mi = 0; mi < 8; ++mi) {
    const int mbase = m0 + wm * 128 + mi * 16 + lg * 4;
#pragma unroll
    for (int ni = 0; ni < 4; ++ni) {
      const int n = n0 + wn * 64 + ni * 16 + lr;
      const float bv = bias[n];
      if (EPI == 1) {
#pragma unroll
        for (int r = 0; r < 4; ++r)
          outf[(size_t)(mbase + r) * N + n] = acc[mi][ni][r] + bv;
      } else {
        const int which = n >> 11;           // 0=q 1=k 2=v
        const int cc = n & 2047, h = cc >> 7, dd = cc & 127;
        const int b = mbase >> 11, t0 = mbase & 2047;  // 4-row group never
        const int bh = b * 16 + h;                     // crosses b boundary
        if (which == 2) {
          bf16x4 pk;
#pragma unroll
          for (int r = 0; r < 4; ++r) pk[r] = (bf16)(acc[mi][ni][r] + bv);
          *(bf16x4*)&vtb[((size_t)bh * 128 + dd) * 2048 + t0] = pk;
        } else {
          bf16* dst = (which == 0) ? qb : kb;
#pragma unroll
          for (int r = 0; r < 4; ++r)
            dst[((size_t)bh * 2048 + t0 + r) * 128 + dd] =
                (bf16)(acc[mi][ni][r] + bv);
        }
      }
    }
  }
}

// ---------------------------------------------------------------------------
// Flash attention, causal, WORK-BALANCED pairing, SWAPPED QK^T, KVBLK=128,
// XCD-AFFINE GRID (64,8). (R21/R22 measured-good version, restored.)
__global__ __launch_bounds__(512) void attn_kernel(
    const bf16* __restrict__ qb, const bf16* __restrict__ kb,
    const bf16* __restrict__ vtb, bf16* __restrict__ ob) {
  __shared__ bf16 Ks[2][128 * 128];  // 64 KB, swizzled
  __shared__ bf16 Vs[2][128 * 128];  // 64 KB, swizzled ([d][t])
  __shared__ bf16 Ps[8][16 * 64];    // 16 KB, swizzled
  const int tid = threadIdx.x, lane = tid & 63, w = tid >> 6;
  const int bh = blockIdx.x;             // XCD affinity: xcd = bh % 8
  const int qtA = blockIdx.y;            // 0..7
  const int qtB = 15 - qtA;              // 8..15
  const int qt_w = (w < 4) ? qtA : qtB;  // this wave's q-tile
  const int wq = w & 3;                  // wave slot within its q-tile
  const int lr = lane & 15, lg = lane >> 4;
  const int q0 = qt_w * 128;
  const size_t base = (size_t)bh * (2048 * 128);
  const int rswz = (lr & 7) << 3;  // row-XOR (element domain)

  // hoist Q frags; fold (1/sqrt(D))*log2(e) so softmax runs in exp2 domain
  const float qscale = 0.08838834764831845f * 1.4426950408889634f;
  bf16x8 qf[2][4];
#pragma unroll
  for (int g = 0; g < 2; ++g) {
    const bf16* qp =
        qb + base + (size_t)(q0 + g * 64 + wq * 16 + lr) * 128 + lg * 8;
#pragma unroll
    for (int kk = 0; kk < 4; ++kk) {
      bf16x8 t = *(const bf16x8*)(qp + kk * 32);
#pragma unroll
      for (int e = 0; e < 8; ++e) t[e] = (bf16)((float)t[e] * qscale);
      qf[g][kk] = t;
    }
  }

  f32x4 o[2][8] = {};
  float mst[2] = {-1e30f, -1e30f};  // running max for q = lr (exp2 domain)
  float lst[2] = {0.f, 0.f};        // running sum for q = lr

  // stage 128-wide tile kt: K 32KB + V 32KB; 8 gload_lds/thread.
  auto STAGE = [&](int bsel, int kt) {
#pragma unroll
    for (int c = 0; c < 4; ++c) {
      const int off = w * 1024 + c * 8192 + lane * 16;  // byte off in 32KB
      const int row = off >> 8, ce = (off & 255) >> 1;  // 256B rows
      gload_lds16(kb + base + (size_t)(kt * 128 + row) * 128 +
                      (ce ^ ((row & 7) << 3)),
                  (char*)Ks[bsel] + w * 1024 + c * 8192);
      gload_lds16(vtb + base + (size_t)row * 2048 + kt * 128 +
                      (ce ^ ((row & 7) << 3)),
                  (char*)Vs[bsel] + w * 1024 + c * 8192);
    }
  };

  const int nst = qtB + 1;  // 128-wide tiles (covers A's range too)
  STAGE(0, 0);              // 8 outstanding
  for (int kt = 0; kt < nst; ++kt) {
    const int cur = kt & 1;
    if (kt + 1 < nst) {
      STAGE(cur ^ 1, kt + 1);  // 8 more in flight
      asm volatile("s_waitcnt vmcnt(8)" ::: "memory");  // tile kt landed
    } else {
      asm volatile("s_waitcnt vmcnt(0)" ::: "memory");
    }
    __builtin_amdgcn_s_barrier();  // all waves' staging of kt visible
    __builtin_amdgcn_sched_barrier(0);

    const bf16* Kc = Ks[cur];
    const bf16* Vc = Vs[cur];
#pragma unroll
    for (int g = 0; g < 2; ++g) {
      const int gb = 2 * qt_w + g;       // global 64-row q-group index
      const int gbrel = gb - 2 * kt;     // tile covers k-blocks 2kt,2kt+1
      if (gbrel < 0) continue;           // wave-uniform: past diagonal

      // S' = K Q^T (swapped): s[j], k_rel = j*16+lg*4+r (0..127), q = lr
      f32x4 s[8] = {};
      __builtin_amdgcn_s_setprio(1);
#pragma unroll
      for (int kk = 0; kk < 4; ++kk)
#pragma unroll
        for (int j = 0; j < 8; ++j) {
          const bf16x8 kf = *(const bf16x8*)&Kc[(j * 16 + lr) * 128 +
                                               ((kk * 32 + lg * 8) ^ rswz)];
          s[j] = __builtin_amdgcn_mfma_f32_16x16x32_bf16(kf, qf[g][kk], s[j],
                                                         0, 0, 0);
        }
      __builtin_amdgcn_s_setprio(0);

      if (gbrel <= 1) {  // diagonal lives in this tile
        const int qq = gbrel * 64 + wq * 16 + lr;  // diag threshold (k units)
#pragma unroll
        for (int j = 0; j < 8; ++j)
#pragma unroll
          for (int r = 0; r < 4; ++r)
            if (j * 16 + lg * 4 + r > qq) s[j][r] = -1e30f;
      }

      // in-lane softmax for q = lr (32 values in this lane)
      float pm;
      {
        float a0 = -1e30f, a1 = -1e30f;
#pragma unroll
        for (int j = 0; j < 8; j += 2) {
          a0 = fmaxf(a0, fmaxf(fmaxf(s[j][0], s[j][1]),
                               fmaxf(s[j][2], s[j][3])));
          a1 = fmaxf(a1, fmaxf(fmaxf(s[j + 1][0], s[j + 1][1]),
                               fmaxf(s[j + 1][2], s[j + 1][3])));
        }
        pm = fmaxf(a0, a1);
      }
      pm = fmaxf(pm, __shfl_xor(pm, 16));
      pm = fmaxf(pm, __shfl_xor(pm, 32));

      // T13 defer-max: rescale only when some row's max grew by >8
      if (__any(pm > mst[g] + 8.0f)) {
        const float mnew = fmaxf(mst[g], pm);
        const float alpha = __builtin_amdgcn_exp2f(mst[g] - mnew);
        mst[g] = mnew;
        lst[g] *= alpha;
#pragma unroll
        for (int r = 0; r < 4; ++r) {  // o rows: q = lg*4+r
          const float av = __shfl(alpha, (lane & 48) | (lg * 4 + r));
#pragma unroll
          for (int n = 0; n < 8; ++n) o[g][n][r] *= av;
        }
      }

      // P = exp2(s - m); in-lane sum + 2 shfl
      float rs = 0.f;
#pragma unroll
      for (int j = 0; j < 8; ++j)
#pragma unroll
        for (int r = 0; r < 4; ++r) {
          const float p = __builtin_amdgcn_exp2f(s[j][r] - mst[g]);
          s[j][r] = p;
          rs += p;
        }
      rs += __shfl_xor(rs, 16);
      rs += __shfl_xor(rs, 32);
      lst[g] += rs;

      // P @ V in two K=64 halves through the per-wave Ps buffer
      __builtin_amdgcn_s_setprio(1);
#pragma unroll
      for (int h = 0; h < 2; ++h) {
#pragma unroll
        for (int j2 = 0; j2 < 4; ++j2) {
          const int j = h * 4 + j2;
          bf16x4 pw;
#pragma unroll
          for (int r = 0; r < 4; ++r) pw[r] = (bf16)s[j][r];
          *(bf16x4*)&Ps[w][lr * 64 + ((j2 * 16 + lg * 4) ^ rswz)] = pw;
        }
        bf16x8 pf[2];
#pragma unroll
        for (int kk = 0; kk < 2; ++kk)
          pf[kk] = *(const bf16x8*)&Ps[w][lr * 64 +
                                         ((kk * 32 + lg * 8) ^ rswz)];
#pragma unroll
        for (int n = 0; n < 8; ++n)
#pragma unroll
          for (int kk = 0; kk < 2; ++kk) {
            const bf16x8 vf = *(const bf16x8*)&Vc[(n * 16 + lr) * 128 +
                                                 ((h * 64 + kk * 32 +
                                                   lg * 8) ^ rswz)];
            o[g][n] = __builtin_amdgcn_mfma_f32_16x16x32_bf16(
                pf[kk], vf, o[g][n], 0, 0, 0);
          }
      }
      __builtin_amdgcn_s_setprio(0);
    }
    __builtin_amdgcn_sched_barrier(0);
    __builtin_amdgcn_s_barrier();  // all reads of buf cur done before next
    __builtin_amdgcn_sched_barrier(0);  // STAGE overwrites it
  }

  // write attn-out as bf16 [B*T][C]; lst holds q=lr, o rows are q=lg*4+r
  const int b = bh >> 4, h = bh & 15;
#pragma unroll
  for (int g = 0; g < 2; ++g)
#pragma unroll
    for (int r = 0; r < 4; ++r) {
      const float inv = 1.0f / __shfl(lst[g], (lane & 48) | (lg * 4 + r));
      const int t = q0 + g * 64 + wq * 16 + lg * 4 + r;
      bf16* dst = ob + ((size_t)(b * 2048 + t)) * 2048 + h * 128;
#pragma unroll
      for (int n = 0; n < 8; ++n) dst[n * 16 + lr] = (bf16)(o[g][n][r] * inv);
    }
}

// ---------------------------------------------------------------------------
extern "C" void kernel_launch(void* const* d_in, const int* in_sizes, int n_in,
                              void* d_out, int out_size, void* d_ws,
                              size_t ws_size, hipStream_t stream) {
  const float* x = (const float*)d_in[0];      // [4,2048,2048]
  const float* Wqkv = (const float*)d_in[1];   // [2048,6144]
  const float* bqkv = (const float*)d_in[2];   // [6144]
  const float* Wproj = (const float*)d_in[3];  // [2048,2048]
  const float* bproj = (const float*)d_in[4];  // [2048]
  float* out = (float*)d_out;                  // [8192,2048] fp32

  char* ws = (char*)d_ws;  // needs ~192 MiB
  bf16* xb     = (bf16*)(ws);                  // 33554432 B  x bf16
  bf16* wqkvT  = (bf16*)(ws + 33554432);       // 25165824 B  Wqkv^T
  bf16* wprojT = (bf16*)(ws + 58720256);       //  8388608 B  Wproj^T
  bf16* qb     = (bf16*)(ws + 67108864);       // 33554432 B  Q [BH][T][D]
  bf16* kb     = (bf16*)(ws + 100663296);      // 33554432 B  K [BH][T][D]
  bf16* vtb    = (bf16*)(ws + 134217728);      // 33554432 B  V^T [BH][D][T]
  bf16* ab     = (bf16*)(ws + 167772160);      // 33554432 B  attn out bf16

  prep_kernel<<<6144, 256, 0, stream>>>(x, xb, Wqkv, wqkvT, Wproj, wprojT);
  gemm256<0><<<768, 512, 0, stream>>>(xb, wqkvT, bqkv, 8192, 6144, 2048,
                                      nullptr, qb, kb, vtb);
  attn_kernel<<<dim3(64, 8), 512, 0, stream>>>(qb, kb, vtb, ab);
  gemm256<1><<<256, 512, 0, stream>>>(ab, wprojT, bproj, 8192, 2048, 2048,
                                      out, nullptr, nullptr, nullptr);
}

// Round 25
// 426.472 us; speedup vs baseline: 1.2777x; 1.0001x over previous
//
#include <hip/hip_runtime.h>

// ---------------------------------------------------------------------------
// Fused MHA: qkv = x@Wqkv+b ; causal attention ; out = attn@Wproj+b
// B=4, T=2048, C=2048, H=16, D=128. fp32 in/out, bf16 MFMA internally.
// GEMM = m201 8-PHASE schedule, WALLS REMOVED this round (no lgkmcnt(0)/
// sched_barrier before the MFMA cluster -- compiler emits fine-grained
// lgkmcnt so first MFMAs overlap tail ds_reads; m97 finding).
// attn = R21/R22 XCD-affine version. Prep merged (R22).
// ---------------------------------------------------------------------------

typedef __bf16 bf16;
typedef __bf16 bf16x8 __attribute__((ext_vector_type(8)));
typedef __bf16 bf16x4 __attribute__((ext_vector_type(4)));
typedef float f32x4 __attribute__((ext_vector_type(4)));

__device__ __forceinline__ void gload_lds16(const void* g, void* l) {
  __builtin_amdgcn_global_load_lds(
      (const __attribute__((address_space(1))) void*)g,
      (__attribute__((address_space(3))) void*)l, 16, 0, 0);
}

// ---------------------------------------------------------------------------
// transpose body: W [R][C] fp32 -> WT [C][R] bf16, 64x64 tile (G13).
__device__ __forceinline__ void transpose_body(
    const float* __restrict__ in, bf16* __restrict__ out, int R, int C,
    int bx, int by, int t, bf16* tile /*[64*64] swizzled*/) {
  const int r0 = by * 64, c0 = bx * 64;
  const int ri = t >> 2, cseg = (t & 3) * 16;
  const float4* src = (const float4*)&in[(size_t)(r0 + ri) * C + c0 + cseg];
  float4 f0 = src[0], f1 = src[1], f2 = src[2], f3 = src[3];
  bf16x8 h0 = {(bf16)f0.x, (bf16)f0.y, (bf16)f0.z, (bf16)f0.w,
               (bf16)f1.x, (bf16)f1.y, (bf16)f1.z, (bf16)f1.w};
  bf16x8 h1 = {(bf16)f2.x, (bf16)f2.y, (bf16)f2.z, (bf16)f2.w,
               (bf16)f3.x, (bf16)f3.y, (bf16)f3.z, (bf16)f3.w};
  const int kx = (ri & 7) << 3;
  *(bf16x8*)&tile[ri * 64 + (cseg ^ kx)] = h0;
  *(bf16x8*)&tile[ri * 64 + ((cseg + 8) ^ kx)] = h1;
  __syncthreads();
  const int oj = t >> 2, rseg = (t & 3) * 16;
  bf16 v[16];
#pragma unroll
  for (int i = 0; i < 16; ++i) {
    const int rr = rseg + i;
    v[i] = tile[rr * 64 + (oj ^ ((rr & 7) << 3))];
  }
  bf16* dst = &out[(size_t)(c0 + oj) * R + r0 + rseg];
  *(bf16x8*)dst = *(bf16x8*)&v[0];
  *(bf16x8*)(dst + 8) = *(bf16x8*)&v[8];
}

// ---------------------------------------------------------------------------
// merged prep: blocks 0..2047 cast x; 2048..5119 transpose Wqkv (96x32);
// 5120..6143 transpose Wproj (32x32). One launch -> streams overlap.
__global__ __launch_bounds__(256) void prep_kernel(
    const float* __restrict__ x, bf16* __restrict__ xb,
    const float* __restrict__ Wqkv, bf16* __restrict__ wqkvT,
    const float* __restrict__ Wproj, bf16* __restrict__ wprojT) {
  __shared__ bf16 tile[64 * 64];  // used by transpose roles only
  const int b = blockIdx.x, t = threadIdx.x;
  if (b < 2048) {  // cast fp32 -> bf16, 8 elems/thread, grid-stride
    for (int i = b * 256 + t; i < 2097152; i += 2048 * 256) {
      const float4* p = (const float4*)x + (size_t)i * 2;
      float4 a = p[0], c = p[1];
      bf16x8 o8 = {(bf16)a.x, (bf16)a.y, (bf16)a.z, (bf16)a.w,
                   (bf16)c.x, (bf16)c.y, (bf16)c.z, (bf16)c.w};
      *(bf16x8*)(xb + (size_t)i * 8) = o8;
    }
  } else if (b < 5120) {  // Wqkv [2048][6144] -> wqkvT [6144][2048]
    const int tb = b - 2048;
    transpose_body(Wqkv, wqkvT, 2048, 6144, tb % 96, tb / 96, t, tile);
  } else {  // Wproj [2048][2048] -> wprojT [2048][2048]
    const int tb = b - 5120;
    transpose_body(Wproj, wprojT, 2048, 2048, tb % 32, tb / 32, t, tile);
  }
}

// ---------------------------------------------------------------------------
// 256x256 GEMM, m201 8-PHASE schedule, no lgkm walls (compiler-scheduled
// fine-grained lgkmcnt). Iteration = 2 K-tiles (a even -> dbuf0, b ->
// dbuf1). Phase = quadrant (dbuf,kh,mhalf):
//   {4-8 ds_read_b128 ; 1 half-tile stage ; barrier ; setprio + 16 MFMA
//    (waits compiler-inserted) ; [vmcnt(4) at ph4/ph8] ; barrier}
template <int EPI>
__global__ __launch_bounds__(512, 2) void gemm256(
    const bf16* __restrict__ A, const bf16* __restrict__ BT,
    const float* __restrict__ bias, int M, int N, int K,
    float* __restrict__ outf, bf16* __restrict__ qb, bf16* __restrict__ kb,
    bf16* __restrict__ vtb) {
  __shared__ bf16 As[2][2][256 * 32];  // 64 KB
  __shared__ bf16 Bs[2][2][256 * 32];  // 64 KB
  const int tid = threadIdx.x;
  const int lane = tid & 63, w = tid >> 6;
  const int wm = w >> 2, wn = w & 3;
  const int lr = lane & 15, lg = lane >> 4;

  // XCD column-major walk (M/256 == 32 == 8 XCDs x 4 m-tiles, both grids)
  const int xcd = blockIdx.x & 7, local = blockIdx.x >> 3;
  const int mt = xcd * 4 + (local & 3), nt = local >> 2;
  const int m0 = mt * 256, n0 = nt * 256;

  // stage one 16KB half-tile (kh, operand) of K-tile kt into dbuf kt&1.
  auto STAGE_H = [&](int skh, int sisB, int kt) {
    const bf16* src = sisB ? BT : A;
    const int r0 = sisB ? n0 : m0;
    bf16* lb = sisB ? &Bs[kt & 1][skh][0] : &As[kt & 1][skh][0];
#pragma unroll
    for (int c = 0; c < 2; ++c) {
      const int chunk = w * 2 + c;                    // 0..15 (1KB chunks)
      const int row = chunk * 16 + (lane >> 2);       // 0..255
      const int col = ((lane & 3) * 8) ^ (((row >> 3) & 1) << 4);
      gload_lds16(src + (size_t)(r0 + row) * K + kt * 64 + skh * 32 + col,
                  (char*)lb + chunk * 1024);
    }
  };
  // fragment reads (swizzled): logical (row, lg*8..+7) of K-half kh
  auto LDA = [&](int d, int kh, int mi) -> bf16x8 {
    const int row = wm * 128 + mi * 16 + lr;
    return *(const bf16x8*)((const char*)&As[d][kh][0] +
                            ((row * 64 + lg * 16) ^ ((lr >> 3) << 5)));
  };
  auto LDB = [&](int d, int kh, int ni) -> bf16x8 {
    const int row = wn * 64 + ni * 16 + lr;
    return *(const bf16x8*)((const char*)&Bs[d][kh][0] +
                            ((row * 64 + lg * 16) ^ ((lr >> 3) << 5)));
  };

  f32x4 acc[8][4] = {};
  bf16x8 bfr[4];
  const int NT = K >> 6;

  // one phase: quadrant (d, kh, mh); stage half-tile (skh,sB) of tile st;
  // vm: -1 none, 4 counted, 0 drain. No lgkm wall: compiler inserts
  // fine-grained lgkmcnt before each MFMA's first fragment use.
  auto PHASE = [&](int d, int kh, int mh, int st, int skh, int sB, int vm) {
    if (mh == 0) {
#pragma unroll
      for (int ni = 0; ni < 4; ++ni) bfr[ni] = LDB(d, kh, ni);
    }
    bf16x8 af4[4];
#pragma unroll
    for (int j = 0; j < 4; ++j) af4[j] = LDA(d, kh, mh * 4 + j);
    if (st < NT) STAGE_H(skh, sB, st);
    __builtin_amdgcn_s_barrier();
    __builtin_amdgcn_s_setprio(1);
#pragma unroll
    for (int j = 0; j < 4; ++j)
#pragma unroll
      for (int ni = 0; ni < 4; ++ni)
        acc[mh * 4 + j][ni] = __builtin_amdgcn_mfma_f32_16x16x32_bf16(
            af4[j], bfr[ni], acc[mh * 4 + j][ni], 0, 0, 0);
    __builtin_amdgcn_s_setprio(0);
    if (vm == 4) asm volatile("s_waitcnt vmcnt(4)" ::: "memory");
    else if (vm == 0) asm volatile("s_waitcnt vmcnt(0)" ::: "memory");
    __builtin_amdgcn_s_barrier();
  };

  // prologue: tile0 fully + tile1 kh0 (12 loads); first 8 (tile0) landed
  STAGE_H(0, 0, 0);
  STAGE_H(0, 1, 0);
  STAGE_H(1, 0, 0);
  STAGE_H(1, 1, 0);
  STAGE_H(0, 0, 1);
  STAGE_H(0, 1, 1);
  asm volatile("s_waitcnt vmcnt(4)" ::: "memory");
  __builtin_amdgcn_s_barrier();

  for (int a = 0; a < NT; a += 2) {
    const int b = a + 1;
    const bool p34 = (a + 2 < NT);
    PHASE(0, 0, 0, b, 1, 0, -1);              // ph1: stage A(b)kh1
    PHASE(0, 0, 1, b, 1, 1, -1);              // ph2: stage B(b)kh1
    PHASE(0, 1, 0, a + 2, 0, 0, -1);          // ph3: stage A(a+2)kh0
    PHASE(0, 1, 1, a + 2, 0, 1, p34 ? 4 : 0); // ph4 (+vmcnt)
    PHASE(1, 0, 0, a + 2, 1, 0, -1);          // ph5: stage A(a+2)kh1
    PHASE(1, 0, 1, a + 2, 1, 1, -1);          // ph6: stage B(a+2)kh1
    PHASE(1, 1, 0, b + 2, 0, 0, -1);          // ph7: stage A(b+2)kh0
    PHASE(1, 1, 1, b + 2, 0, 1, p34 ? 4 : 0); // ph8 (+vmcnt)
  }

  // epilogue: C/D layout col=lane&15, row=(lane>>4)*4+r  [m89/m91]
#pragma unroll
  for (int mi = 0; mi < 8; ++mi) {
    const int mbase = m0 + wm * 128 + mi * 16 + lg * 4;
#pragma unroll
    for (int ni = 0; ni < 4; ++ni) {
      const int n = n0 + wn * 64 + ni * 16 + lr;
      const float bv = bias[n];
      if (EPI == 1) {
#pragma unroll
        for (int r = 0; r < 4; ++r)
          outf[(size_t)(mbase + r) * N + n] = acc[mi][ni][r] + bv;
      } else {
        const int which = n >> 11;           // 0=q 1=k 2=v
        const int cc = n & 2047, h = cc >> 7, dd = cc & 127;
        const int b = mbase >> 11, t0 = mbase & 2047;  // 4-row group never
        const int bh = b * 16 + h;                     // crosses b boundary
        if (which == 2) {
          bf16x4 pk;
#pragma unroll
          for (int r = 0; r < 4; ++r) pk[r] = (bf16)(acc[mi][ni][r] + bv);
          *(bf16x4*)&vtb[((size_t)bh * 128 + dd) * 2048 + t0] = pk;
        } else {
          bf16* dst = (which == 0) ? qb : kb;
#pragma unroll
          for (int r = 0; r < 4; ++r)
            dst[((size_t)bh * 2048 + t0 + r) * 128 + dd] =
                (bf16)(acc[mi][ni][r] + bv);
        }
      }
    }
  }
}

// ---------------------------------------------------------------------------
// Flash attention, causal, WORK-BALANCED pairing, SWAPPED QK^T, KVBLK=128,
// XCD-AFFINE GRID (64,8). (R21/R22 measured-good version, unchanged.)
__global__ __launch_bounds__(512) void attn_kernel(
    const bf16* __restrict__ qb, const bf16* __restrict__ kb,
    const bf16* __restrict__ vtb, bf16* __restrict__ ob) {
  __shared__ bf16 Ks[2][128 * 128];  // 64 KB, swizzled
  __shared__ bf16 Vs[2][128 * 128];  // 64 KB, swizzled ([d][t])
  __shared__ bf16 Ps[8][16 * 64];    // 16 KB, swizzled
  const int tid = threadIdx.x, lane = tid & 63, w = tid >> 6;
  const int bh = blockIdx.x;             // XCD affinity: xcd = bh % 8
  const int qtA = blockIdx.y;            // 0..7
  const int qtB = 15 - qtA;              // 8..15
  const int qt_w = (w < 4) ? qtA : qtB;  // this wave's q-tile
  const int wq = w & 3;                  // wave slot within its q-tile
  const int lr = lane & 15, lg = lane >> 4;
  const int q0 = qt_w * 128;
  const size_t base = (size_t)bh * (2048 * 128);
  const int rswz = (lr & 7) << 3;  // row-XOR (element domain)

  // hoist Q frags; fold (1/sqrt(D))*log2(e) so softmax runs in exp2 domain
  const float qscale = 0.08838834764831845f * 1.4426950408889634f;
  bf16x8 qf[2][4];
#pragma unroll
  for (int g = 0; g < 2; ++g) {
    const bf16* qp =
        qb + base + (size_t)(q0 + g * 64 + wq * 16 + lr) * 128 + lg * 8;
#pragma unroll
    for (int kk = 0; kk < 4; ++kk) {
      bf16x8 t = *(const bf16x8*)(qp + kk * 32);
#pragma unroll
      for (int e = 0; e < 8; ++e) t[e] = (bf16)((float)t[e] * qscale);
      qf[g][kk] = t;
    }
  }

  f32x4 o[2][8] = {};
  float mst[2] = {-1e30f, -1e30f};  // running max for q = lr (exp2 domain)
  float lst[2] = {0.f, 0.f};        // running sum for q = lr

  // stage 128-wide tile kt: K 32KB + V 32KB; 8 gload_lds/thread.
  auto STAGE = [&](int bsel, int kt) {
#pragma unroll
    for (int c = 0; c < 4; ++c) {
      const int off = w * 1024 + c * 8192 + lane * 16;  // byte off in 32KB
      const int row = off >> 8, ce = (off & 255) >> 1;  // 256B rows
      gload_lds16(kb + base + (size_t)(kt * 128 + row) * 128 +
                      (ce ^ ((row & 7) << 3)),
                  (char*)Ks[bsel] + w * 1024 + c * 8192);
      gload_lds16(vtb + base + (size_t)row * 2048 + kt * 128 +
                      (ce ^ ((row & 7) << 3)),
                  (char*)Vs[bsel] + w * 1024 + c * 8192);
    }
  };

  const int nst = qtB + 1;  // 128-wide tiles (covers A's range too)
  STAGE(0, 0);              // 8 outstanding
  for (int kt = 0; kt < nst; ++kt) {
    const int cur = kt & 1;
    if (kt + 1 < nst) {
      STAGE(cur ^ 1, kt + 1);  // 8 more in flight
      asm volatile("s_waitcnt vmcnt(8)" ::: "memory");  // tile kt landed
    } else {
      asm volatile("s_waitcnt vmcnt(0)" ::: "memory");
    }
    __builtin_amdgcn_s_barrier();  // all waves' staging of kt visible
    __builtin_amdgcn_sched_barrier(0);

    const bf16* Kc = Ks[cur];
    const bf16* Vc = Vs[cur];
#pragma unroll
    for (int g = 0; g < 2; ++g) {
      const int gb = 2 * qt_w + g;       // global 64-row q-group index
      const int gbrel = gb - 2 * kt;     // tile covers k-blocks 2kt,2kt+1
      if (gbrel < 0) continue;           // wave-uniform: past diagonal

      // S' = K Q^T (swapped): s[j], k_rel = j*16+lg*4+r (0..127), q = lr
      f32x4 s[8] = {};
      __builtin_amdgcn_s_setprio(1);
#pragma unroll
      for (int kk = 0; kk < 4; ++kk)
#pragma unroll
        for (int j = 0; j < 8; ++j) {
          const bf16x8 kf = *(const bf16x8*)&Kc[(j * 16 + lr) * 128 +
                                               ((kk * 32 + lg * 8) ^ rswz)];
          s[j] = __builtin_amdgcn_mfma_f32_16x16x32_bf16(kf, qf[g][kk], s[j],
                                                         0, 0, 0);
        }
      __builtin_amdgcn_s_setprio(0);

      if (gbrel <= 1) {  // diagonal lives in this tile
        const int qq = gbrel * 64 + wq * 16 + lr;  // diag threshold (k units)
#pragma unroll
        for (int j = 0; j < 8; ++j)
#pragma unroll
          for (int r = 0; r < 4; ++r)
            if (j * 16 + lg * 4 + r > qq) s[j][r] = -1e30f;
      }

      // in-lane softmax for q = lr (32 values in this lane)
      float pm;
      {
        float a0 = -1e30f, a1 = -1e30f;
#pragma unroll
        for (int j = 0; j < 8; j += 2) {
          a0 = fmaxf(a0, fmaxf(fmaxf(s[j][0], s[j][1]),
                               fmaxf(s[j][2], s[j][3])));
          a1 = fmaxf(a1, fmaxf(fmaxf(s[j + 1][0], s[j + 1][1]),
                               fmaxf(s[j + 1][2], s[j + 1][3])));
        }
        pm = fmaxf(a0, a1);
      }
      pm = fmaxf(pm, __shfl_xor(pm, 16));
      pm = fmaxf(pm, __shfl_xor(pm, 32));

      // T13 defer-max: rescale only when some row's max grew by >8
      if (__any(pm > mst[g] + 8.0f)) {
        const float mnew = fmaxf(mst[g], pm);
        const float alpha = __builtin_amdgcn_exp2f(mst[g] - mnew);
        mst[g] = mnew;
        lst[g] *= alpha;
#pragma unroll
        for (int r = 0; r < 4; ++r) {  // o rows: q = lg*4+r
          const float av = __shfl(alpha, (lane & 48) | (lg * 4 + r));
#pragma unroll
          for (int n = 0; n < 8; ++n) o[g][n][r] *= av;
        }
      }

      // P = exp2(s - m); in-lane sum + 2 shfl
      float rs = 0.f;
#pragma unroll
      for (int j = 0; j < 8; ++j)
#pragma unroll
        for (int r = 0; r < 4; ++r) {
          const float p = __builtin_amdgcn_exp2f(s[j][r] - mst[g]);
          s[j][r] = p;
          rs += p;
        }
      rs += __shfl_xor(rs, 16);
      rs += __shfl_xor(rs, 32);
      lst[g] += rs;

      // P @ V in two K=64 halves through the per-wave Ps buffer
      __builtin_amdgcn_s_setprio(1);
#pragma unroll
      for (int h = 0; h < 2; ++h) {
#pragma unroll
        for (int j2 = 0; j2 < 4; ++j2) {
          const int j = h * 4 + j2;
          bf16x4 pw;
#pragma unroll
          for (int r = 0; r < 4; ++r) pw[r] = (bf16)s[j][r];
          *(bf16x4*)&Ps[w][lr * 64 + ((j2 * 16 + lg * 4) ^ rswz)] = pw;
        }
        bf16x8 pf[2];
#pragma unroll
        for (int kk = 0; kk < 2; ++kk)
          pf[kk] = *(const bf16x8*)&Ps[w][lr * 64 +
                                         ((kk * 32 + lg * 8) ^ rswz)];
#pragma unroll
        for (int n = 0; n < 8; ++n)
#pragma unroll
          for (int kk = 0; kk < 2; ++kk) {
            const bf16x8 vf = *(const bf16x8*)&Vc[(n * 16 + lr) * 128 +
                                                 ((h * 64 + kk * 32 +
                                                   lg * 8) ^ rswz)];
            o[g][n] = __builtin_amdgcn_mfma_f32_16x16x32_bf16(
                pf[kk], vf, o[g][n], 0, 0, 0);
          }
      }
      __builtin_amdgcn_s_setprio(0);
    }
    __builtin_amdgcn_sched_barrier(0);
    __builtin_amdgcn_s_barrier();  // all reads of buf cur done before next
    __builtin_amdgcn_sched_barrier(0);  // STAGE overwrites it
  }

  // write attn-out as bf16 [B*T][C]; lst holds q=lr, o rows are q=lg*4+r
  const int b = bh >> 4, h = bh & 15;
#pragma unroll
  for (int g = 0; g < 2; ++g)
#pragma unroll
    for (int r = 0; r < 4; ++r) {
      const float inv = 1.0f / __shfl(lst[g], (lane & 48) | (lg * 4 + r));
      const int t = q0 + g * 64 + wq * 16 + lg * 4 + r;
      bf16* dst = ob + ((size_t)(b * 2048 + t)) * 2048 + h * 128;
#pragma unroll
      for (int n = 0; n < 8; ++n) dst[n * 16 + lr] = (bf16)(o[g][n][r] * inv);
    }
}

// ---------------------------------------------------------------------------
extern "C" void kernel_launch(void* const* d_in, const int* in_sizes, int n_in,
                              void* d_out, int out_size, void* d_ws,
                              size_t ws_size, hipStream_t stream) {
  const float* x = (const float*)d_in[0];      // [4,2048,2048]
  const float* Wqkv = (const float*)d_in[1];   // [2048,6144]
  const float* bqkv = (const float*)d_in[2];   // [6144]
  const float* Wproj = (const float*)d_in[3];  // [2048,2048]
  const float* bproj = (const float*)d_in[4];  // [2048]
  float* out = (float*)d_out;                  // [8192,2048] fp32

  char* ws = (char*)d_ws;  // needs ~192 MiB
  bf16* xb     = (bf16*)(ws);                  // 33554432 B  x bf16
  bf16* wqkvT  = (bf16*)(ws + 33554432);       // 25165824 B  Wqkv^T
  bf16* wprojT = (bf16*)(ws + 58720256);       //  8388608 B  Wproj^T
  bf16* qb     = (bf16*)(ws + 67108864);       // 33554432 B  Q [BH][T][D]
  bf16* kb     = (bf16*)(ws + 100663296);      // 33554432 B  K [BH][T][D]
  bf16* vtb    = (bf16*)(ws + 134217728);      // 33554432 B  V^T [BH][D][T]
  bf16* ab     = (bf16*)(ws + 167772160);      // 33554432 B  attn out bf16

  prep_kernel<<<6144, 256, 0, stream>>>(x, xb, Wqkv, wqkvT, Wproj, wprojT);
  gemm256<0><<<768, 512, 0, stream>>>(xb, wqkvT, bqkv, 8192, 6144, 2048,
                                      nullptr, qb, kb, vtb);
  attn_kernel<<<dim3(64, 8), 512, 0, stream>>>(qb, kb, vtb, ab);
  gemm256<1><<<256, 512, 0, stream>>>(ab, wprojT, bproj, 8192, 2048, 2048,
                                      out, nullptr, nullptr, nullptr);
}